// Round 11
// baseline (810.672 us; speedup 1.0000x reference)
//
#include <hip/hip_runtime.h>
#include <cfloat>

// E8 codebook quantize: per row of X[N][8]
//   neg mask, parity -> X_part = |X| with coord0 sign-fixed
//   scores = 2*dot - norm, argmax (first-max), vals/idx via sign-unflip + gather
//
// GOLDEN SCORING CHAIN (verified absmax=0 in R8/R9 — DO NOT CHANGE):
//   p_i = fl(x_i * g_i); q_i = fl(p_i + p_{i+4});
//   d = fl(fl(q0+q1)+fl(q2+q3)); s = fmaf(2,d,-n)  [== fl(fl(2d)-n), 2d exact]
//
// R11: R10's ext_vector pk experiment REVERTED (regressed 411->508: no v_pk
// selected, s_load batching broken). Inner loop is byte-for-byte R9.
// New: wave-pair P-split for occupancy. Wave 2k scans p=[0,P2), wave 2k+1
// scans [P2,P) — both ranges WAVE-UNIFORM so the codebook stays on the
// scalar s_load path (the R9 win). Merge via LDS; upper half wins only on
// strict > (its indices are all larger => first-max preserved exactly).
// Grid doubles to 2048 blocks -> 32 waves/CU (was 16), hiding the s_load
// latency that capped R9 at VALUBusy 66%.
//
// Output d_out (float*): vals [N*8] then real_idx [N] (int stored as float).
// allcombo/idx_map are int32-canonicalized on device (established R1-R3).

__global__ __launch_bounds__(256, 8)
void e8_quant_kernel(const float* __restrict__ X,
                     const float* __restrict__ grid_part,   // [P*8] f32
                     const float* __restrict__ grid_norm,   // [P]   f32
                     const int*   __restrict__ allcombo,    // [128*P] int32
                     const int*   __restrict__ idx_map,     // [256] int32
                     float* __restrict__ out,               // [N*8 + N]
                     int N, int P)
{
    #pragma clang fp contract(off)

    __shared__ float s_best[2][64];
    __shared__ int   s_bidx[2][64];

    int wave   = threadIdx.x >> 6;
    int lane   = threadIdx.x & 63;
    int pairid = wave >> 1;          // 0,1 : two row-groups per block
    int half   = wave & 1;           // 0: p=[0,P2), 1: p=[P2,P)
    int row    = blockIdx.x * 128 + pairid * 64 + lane;   // N % 128 == 0
    if (row >= N) return;            // (never taken for N=262144; safety)

    const float4* xr = reinterpret_cast<const float4*>(X + (size_t)row * 8);
    float4 xa = xr[0];
    float4 xb = xr[1];
    float x[8] = { xa.x, xa.y, xa.z, xa.w, xb.x, xb.y, xb.z, xb.w };

    // neg mask + parity
    unsigned nm = 0u;
    #pragma unroll
    for (int c = 0; c < 8; ++c) nm |= (x[c] < 0.0f) ? (1u << c) : 0u;
    unsigned odd = __popc(nm) & 1u;

    // X_part = |x|, coord0 negated when parity odd (exact sign ops)
    float xp0 = fabsf(x[0]);
    xp0 = odd ? -xp0 : xp0;
    float xp1 = fabsf(x[1]);
    float xp2 = fabsf(x[2]);
    float xp3 = fabsf(x[3]);
    float xp4 = fabsf(x[4]);
    float xp5 = fabsf(x[5]);
    float xp6 = fabsf(x[6]);
    float xp7 = fabsf(x[7]);

    // this wave's codebook half (wave-uniform bounds -> scalar s_load path)
    int P2     = (P + 1) >> 1;
    int pstart = half ? P2 : 0;
    int pend   = half ? P  : P2;

    const float4* gp4 = reinterpret_cast<const float4*>(grid_part);
    float best = -FLT_MAX;
    int   bidx = 0;
    #pragma unroll 4
    for (int p = pstart; p < pend; ++p) {
        float4 ga = gp4[2 * p];
        float4 gb = gp4[2 * p + 1];
        float nrm = grid_norm[p];
        // separately-rounded products (contract off => real v_mul_f32)
        float p0 = xp0 * ga.x;
        float p1 = xp1 * ga.y;
        float p2 = xp2 * ga.z;
        float p3 = xp3 * ga.w;
        float p4 = xp4 * gb.x;
        float p5 = xp5 * gb.y;
        float p6 = xp6 * gb.z;
        float p7 = xp7 * gb.w;
        // 128-bit fold: q_i = p_i + p_{i+4}
        float q0 = p0 + p4;
        float q1 = p1 + p5;
        float q2 = p2 + p6;
        float q3 = p3 + p7;
        // adjacent merge
        float t0 = q0 + q1;
        float t1 = q2 + q3;
        float d  = t0 + t1;
        // s = fl(2d - n): 2d exact, single rounding == fl(fl(2d)-n)
        float s  = fmaf(2.0f, d, -nrm);
        bool gt = (s > best);
        best = gt ? s : best;
        bidx = gt ? p : bidx;
    }

    // merge wave pair: upper half wins only on strict > (first-max exact)
    if (half == 1) {
        s_best[pairid][lane] = best;
        s_bidx[pairid][lane] = bidx;
    }
    __syncthreads();
    if (half == 1) return;
    {
        float bh = s_best[pairid][lane];
        int   ih = s_bidx[pairid][lane];
        if (bh > best) { best = bh; bidx = ih; }
    }

    // packed sign bits: bit c = neg[c] for c>=1, bit0 = neg0 ^ parity
    unsigned packed = (nm & 0xFEu) | ((nm ^ odd) & 1u);

    // vals = grid_part[best] * mask (exact sign flips)
    const float* g = grid_part + (size_t)bidx * 8;
    float v[8];
    #pragma unroll
    for (int c = 0; c < 8; ++c) {
        float gv = g[c];
        v[c] = ((packed >> c) & 1u) ? -gv : gv;
    }
    float4* orow = reinterpret_cast<float4*>(out + (size_t)row * 8);
    float4 o0 = { v[0], v[1], v[2], v[3] };
    float4 o1 = { v[4], v[5], v[6], v[7] };
    orow[0] = o0;
    orow[1] = o1;

    // real_idx = allcombo[idx_map[packed]][best]
    int crow = idx_map[packed];
    int idxv = allcombo[(size_t)crow * P + bidx];
    out[(size_t)N * 8 + row] = (float)idxv;
}

extern "C" void kernel_launch(void* const* d_in, const int* in_sizes, int n_in,
                              void* d_out, int out_size, void* d_ws, size_t ws_size,
                              hipStream_t stream) {
    const float* X        = (const float*)d_in[0];
    const float* gridpart = (const float*)d_in[1];
    const float* gridnorm = (const float*)d_in[2];
    // d_in[3] = int_map (2^c) — hardcoded as bit shifts
    const int*   allcombo = (const int*)d_in[4];
    const int*   idxmap   = (const int*)d_in[5];
    float* out = (float*)d_out;

    int N = in_sizes[0] / 8;
    int P = in_sizes[2];

    int block = 256;                    // 4 waves: 2 row-groups x 2 halves
    int grid  = (N + 127) / 128;        // 128 rows per block

    hipLaunchKernelGGL(e8_quant_kernel, dim3(grid), dim3(block), 0, stream,
                       X, gridpart, gridnorm, allcombo, idxmap, out, N, P);
}

// Round 12
// 440.409 us; speedup vs baseline: 1.8407x; 1.8407x over previous
//
#include <hip/hip_runtime.h>
#include <cfloat>

// E8 codebook quantize: per row of X[N][8]
//   neg mask, parity -> X_part = |X| with coord0 sign-fixed
//   scores = 2*dot - norm, argmax (first-max), vals/idx via sign-unflip + gather
//
// GOLDEN SCORING CHAIN (verified absmax=0 in R8/R9 — DO NOT CHANGE):
//   p_i = fl(x_i * g_i); q_i = fl(p_i + p_{i+4});
//   d = fl(fl(q0+q1)+fl(q2+q3)); s = fmaf(2,d,-n)  [== fl(fl(2d)-n), 2d exact]
//
// R12: R11 post-mortem — wave-pair split lost the scalar s_load path because
// half/pairid derive from threadIdx.x, which LLVM divergence analysis marks
// divergent (SGPR 80->48, VALU-busy time 271->473us: loads became per-lane
// vector loads + address VALU). Fix: launder half/pairid through
// __builtin_amdgcn_readfirstlane -> compiler sees uniform SGPRs -> loop
// bounds uniform -> codebook back on s_load. Keeps R11's 32-wave/CU
// occupancy AND R9's scalarization.
//
// Output d_out (float*): vals [N*8] then real_idx [N] (int stored as float).
// allcombo/idx_map are int32-canonicalized on device (established R1-R3).

__global__ __launch_bounds__(256, 8)
void e8_quant_kernel(const float* __restrict__ X,
                     const float* __restrict__ grid_part,   // [P*8] f32
                     const float* __restrict__ grid_norm,   // [P]   f32
                     const int*   __restrict__ allcombo,    // [128*P] int32
                     const int*   __restrict__ idx_map,     // [256] int32
                     float* __restrict__ out,               // [N*8 + N]
                     int N, int P)
{
    #pragma clang fp contract(off)

    __shared__ float s_best[2][64];
    __shared__ int   s_bidx[2][64];

    int lane   = threadIdx.x & 63;
    // wave-uniform by construction; readfirstlane makes the compiler see it
    int wave   = __builtin_amdgcn_readfirstlane(threadIdx.x >> 6);
    int pairid = wave >> 1;          // 0,1 : two row-groups per block (SGPR)
    int half   = wave & 1;           // 0: p=[0,P2), 1: p=[P2,P)   (SGPR)
    int row    = blockIdx.x * 128 + pairid * 64 + lane;   // N % 128 == 0

    const float4* xr = reinterpret_cast<const float4*>(X + (size_t)row * 8);
    float4 xa = xr[0];
    float4 xb = xr[1];
    float x[8] = { xa.x, xa.y, xa.z, xa.w, xb.x, xb.y, xb.z, xb.w };

    // neg mask + parity
    unsigned nm = 0u;
    #pragma unroll
    for (int c = 0; c < 8; ++c) nm |= (x[c] < 0.0f) ? (1u << c) : 0u;
    unsigned odd = __popc(nm) & 1u;

    // X_part = |x|, coord0 negated when parity odd (exact sign ops)
    float xp0 = fabsf(x[0]);
    xp0 = odd ? -xp0 : xp0;
    float xp1 = fabsf(x[1]);
    float xp2 = fabsf(x[2]);
    float xp3 = fabsf(x[3]);
    float xp4 = fabsf(x[4]);
    float xp5 = fabsf(x[5]);
    float xp6 = fabsf(x[6]);
    float xp7 = fabsf(x[7]);

    // this wave's codebook half — uniform SGPR bounds -> scalar s_load path
    int P2     = (P + 1) >> 1;
    int pstart = half ? P2 : 0;
    int pend   = half ? P  : P2;

    const float4* gp4 = reinterpret_cast<const float4*>(grid_part);
    float best = -FLT_MAX;
    int   bidx = 0;
    #pragma unroll 4
    for (int p = pstart; p < pend; ++p) {
        float4 ga = gp4[2 * p];
        float4 gb = gp4[2 * p + 1];
        float nrm = grid_norm[p];
        // separately-rounded products (contract off => real v_mul_f32)
        float p0 = xp0 * ga.x;
        float p1 = xp1 * ga.y;
        float p2 = xp2 * ga.z;
        float p3 = xp3 * ga.w;
        float p4 = xp4 * gb.x;
        float p5 = xp5 * gb.y;
        float p6 = xp6 * gb.z;
        float p7 = xp7 * gb.w;
        // 128-bit fold: q_i = p_i + p_{i+4}
        float q0 = p0 + p4;
        float q1 = p1 + p5;
        float q2 = p2 + p6;
        float q3 = p3 + p7;
        // adjacent merge
        float t0 = q0 + q1;
        float t1 = q2 + q3;
        float d  = t0 + t1;
        // s = fl(2d - n): 2d exact, single rounding == fl(fl(2d)-n)
        float s  = fmaf(2.0f, d, -nrm);
        bool gt = (s > best);
        best = gt ? s : best;
        bidx = gt ? p : bidx;
    }

    // merge wave pair: upper half wins only on strict > (first-max exact:
    // upper-half indices are all larger, ties keep the lower half's winner)
    if (half == 1) {
        s_best[pairid][lane] = best;
        s_bidx[pairid][lane] = bidx;
    }
    __syncthreads();
    if (half == 1) return;
    {
        float bh = s_best[pairid][lane];
        int   ih = s_bidx[pairid][lane];
        if (bh > best) { best = bh; bidx = ih; }
    }

    // packed sign bits: bit c = neg[c] for c>=1, bit0 = neg0 ^ parity
    unsigned packed = (nm & 0xFEu) | ((nm ^ odd) & 1u);

    // vals = grid_part[best] * mask (exact sign flips)
    const float* g = grid_part + (size_t)bidx * 8;
    float v[8];
    #pragma unroll
    for (int c = 0; c < 8; ++c) {
        float gv = g[c];
        v[c] = ((packed >> c) & 1u) ? -gv : gv;
    }
    float4* orow = reinterpret_cast<float4*>(out + (size_t)row * 8);
    float4 o0 = { v[0], v[1], v[2], v[3] };
    float4 o1 = { v[4], v[5], v[6], v[7] };
    orow[0] = o0;
    orow[1] = o1;

    // real_idx = allcombo[idx_map[packed]][best]
    int crow = idx_map[packed];
    int idxv = allcombo[(size_t)crow * P + bidx];
    out[(size_t)N * 8 + row] = (float)idxv;
}

extern "C" void kernel_launch(void* const* d_in, const int* in_sizes, int n_in,
                              void* d_out, int out_size, void* d_ws, size_t ws_size,
                              hipStream_t stream) {
    const float* X        = (const float*)d_in[0];
    const float* gridpart = (const float*)d_in[1];
    const float* gridnorm = (const float*)d_in[2];
    // d_in[3] = int_map (2^c) — hardcoded as bit shifts
    const int*   allcombo = (const int*)d_in[4];
    const int*   idxmap   = (const int*)d_in[5];
    float* out = (float*)d_out;

    int N = in_sizes[0] / 8;
    int P = in_sizes[2];

    int block = 256;                    // 4 waves: 2 row-groups x 2 halves
    int grid  = (N + 127) / 128;        // 128 rows per block

    hipLaunchKernelGGL(e8_quant_kernel, dim3(grid), dim3(block), 0, stream,
                       X, gridpart, gridnorm, allcombo, idxmap, out, N, P);
}